// Round 7
// baseline (154.828 us; speedup 1.0000x reference)
//
#include <hip/hip_runtime.h>
#include <math.h>

#define NCLS 80
#define NA 8400
#define NB 32
#define NO 144
#define PRE_TOPK 1000
#define MAX_DET 100

// ---------------- Kernel 1: decode, 4 anchors/thread via float4 ----------------
// Channel-major layout: lane loads float4 at base + c*HW (16B/lane -> 1KB/wave
// per instruction, the coalescing sweet spot). All float4 component accesses
// are under fully-unrolled constant indices (no scratch).
__device__ __forceinline__ float comp(const float4& v, int a) {
    return a == 0 ? v.x : a == 1 ? v.y : a == 2 ? v.z : v.w;
}

template<int HW, int WDIM, int S>
__device__ __forceinline__ void decode_store4(
    const float* __restrict__ src, int gq, int aoff,
    float* __restrict__ conf, int* __restrict__ clsid, float* __restrict__ box)
{
    int b = gq / (HW / 4);
    int q = gq - b * (HW / 4);
    int pos0 = q * 4;
    const float* base = src + (size_t)b * (NO * HW) + pos0;

    // DFL: softmax over 16 bins per side, dot with arange(16) — 4 anchors at once
    float dist[4][4];                       // [side][anchor]
    #pragma unroll
    for (int s4 = 0; s4 < 4; ++s4) {
        float4 v[16];
        #pragma unroll
        for (int r = 0; r < 16; ++r) v[r] = *(const float4*)(base + (size_t)(s4 * 16 + r) * HW);
        #pragma unroll
        for (int a = 0; a < 4; ++a) {
            float mm = comp(v[0], a);
            #pragma unroll
            for (int r = 1; r < 16; ++r) mm = fmaxf(mm, comp(v[r], a));
            float sum = 0.f, d = 0.f;
            #pragma unroll
            for (int r = 0; r < 16; ++r) {
                float e = __expf(comp(v[r], a) - mm);
                sum += e;
                d += e * (float)r;
            }
            dist[s4][a] = d * (1.0f / sum);
        }
    }

    // class argmax over logits (sigmoid monotone -> sigmoid(max)), 4 chunks of 20
    float best[4] = {-INFINITY, -INFINITY, -INFINITY, -INFINITY};
    int bid[4] = {0, 0, 0, 0};
    #pragma unroll
    for (int ch = 0; ch < 4; ++ch) {
        float4 vc[20];
        #pragma unroll
        for (int c = 0; c < 20; ++c) vc[c] = *(const float4*)(base + (size_t)(64 + ch * 20 + c) * HW);
        #pragma unroll
        for (int a = 0; a < 4; ++a) {
            float m = comp(vc[0], a); int ii = 0;
            #pragma unroll
            for (int c = 1; c < 20; ++c) {
                float x = comp(vc[c], a);
                if (x > m) { m = x; ii = c; }
            }
            if (m > best[a]) { best[a] = m; bid[a] = ch * 20 + ii; }
        }
    }

    size_t gid0 = (size_t)b * NA + aoff + pos0;
    float4 cv;
    cv.x = 1.0f / (1.0f + __expf(-best[0]));
    cv.y = 1.0f / (1.0f + __expf(-best[1]));
    cv.z = 1.0f / (1.0f + __expf(-best[2]));
    cv.w = 1.0f / (1.0f + __expf(-best[3]));
    *(float4*)(conf + gid0) = cv;
    *(int4*)(clsid + gid0) = make_int4(bid[0], bid[1], bid[2], bid[3]);

    #pragma unroll
    for (int a = 0; a < 4; ++a) {
        int pos = pos0 + a;
        float ax = (float)(pos % WDIM) + 0.5f;
        float ay = (float)(pos / WDIM) + 0.5f;
        float x1 = ax - dist[0][a], y1 = ay - dist[1][a];
        float x2 = ax + dist[2][a], y2 = ay + dist[3][a];
        float cx = ((x1 + x2) * 0.5f) * (float)S;
        float cy = ((y1 + y2) * 0.5f) * (float)S;
        float w  = (x2 - x1) * (float)S;
        float h  = (y2 - y1) * (float)S;
        *(float4*)(box + (gid0 + a) * 4) = make_float4(cx, cy, w, h);
    }
}

// grid: 400 blocks (p3) + 100 (p4) + 25 (p5) = 525 blocks of 128 threads
__global__ __launch_bounds__(128) void k_decode(
    const float* __restrict__ p3, const float* __restrict__ p4, const float* __restrict__ p5,
    float* __restrict__ conf, int* __restrict__ clsid, float* __restrict__ box)
{
    int blk = blockIdx.x;
    int t = threadIdx.x;
    if (blk < 400) {            // p3: 32 b * 1600 quad-groups
        int gq = blk * 128 + t;
        decode_store4<6400, 80, 8>(p3, gq, 0, conf, clsid, box);
    } else if (blk < 500) {     // p4: 32 * 400
        int gq = (blk - 400) * 128 + t;
        decode_store4<1600, 40, 16>(p4, gq, 6400, conf, clsid, box);
    } else {                    // p5: 32 * 100
        int gq = (blk - 500) * 128 + t;
        decode_store4<400, 20, 32>(p5, gq, 8000, conf, clsid, box);
    }
}

// ---------------- Kernel 2: exact stable top-1000 per batch ----------------
__device__ __forceinline__ uint32_t ord_bits(float f) {
    uint32_t u = __float_as_uint(f);
    return (u & 0x80000000u) ? ~u : (u | 0x80000000u);
}

__global__ __launch_bounds__(1024) void k_select(
    const float* __restrict__ conf, const float* __restrict__ box, const int* __restrict__ clsid,
    float* __restrict__ topv, float* __restrict__ bxyxy, int* __restrict__ topcls)
{
    int b = blockIdx.x;
    int t = threadIdx.x;
    int lane = t & 63;

    __shared__ uint32_t ob[NA];          // 33.6 KB
    __shared__ uint32_t hist[256];
    __shared__ uint64_t sbuf[1024];      // 8 KB
    __shared__ uint64_t s_prefix;
    __shared__ int s_k;
    __shared__ int s_cnt;

    const float* cf = conf + (size_t)b * NA;
    for (int i = t; i < NA; i += 1024) {
        float c = cf[i];
        float cm = (c > 0.25f) ? c : -1.0f;
        ob[i] = ord_bits(cm);
    }
    if (t == 0) { s_prefix = 0; s_k = PRE_TOPK; s_cnt = 0; }
    sbuf[t] = 0;
    __syncthreads();

    // radix-select exact rank-1000 key; wave-aggregated histogram atomics
    for (int pass = 0; pass < 8; ++pass) {
        int shift = 56 - 8 * pass;
        if (t < 256) hist[t] = 0;
        __syncthreads();
        uint64_t prefix = s_prefix;
        int k = s_k;
        for (int i = t; i < NA; i += 1024) {
            uint64_t key = ((uint64_t)ob[i] << 32) | (uint64_t)(0xFFFFFFFFu - (uint32_t)i);
            bool match = (pass == 0) || (((key ^ prefix) >> (64 - 8 * pass)) == 0);
            uint32_t d = (uint32_t)(key >> shift) & 255u;
            if (match) {
                uint64_t m = __ballot(1);
                #pragma unroll
                for (int bb = 0; bb < 8; ++bb) {
                    uint64_t bal = __ballot((d >> bb) & 1u);
                    m &= ((d >> bb) & 1u) ? bal : ~bal;
                }
                if ((m & ((1ull << lane) - 1ull)) == 0ull)
                    atomicAdd(&hist[d], (uint32_t)__popcll(m));
            }
        }
        __syncthreads();
        if (t < 64) {   // wave-0 suffix-scan digit selection
            uint32_t h0 = hist[4 * t + 0], h1 = hist[4 * t + 1];
            uint32_t h2 = hist[4 * t + 2], h3 = hist[4 * t + 3];
            uint32_t part = h0 + h1 + h2 + h3;
            uint32_t s = part;
            #pragma unroll
            for (int off = 1; off < 64; off <<= 1) {
                uint32_t v = __shfl_down(s, off);
                if (t + off < 64) s += v;
            }
            uint32_t cb3 = s - part;
            uint32_t cb2 = cb3 + h3;
            uint32_t cb1 = cb2 + h2;
            uint32_t cb0 = cb1 + h1;
            uint32_t ku = (uint32_t)k;
            if (cb3 < ku && ku <= cb3 + h3) { s_k = k - (int)cb3; s_prefix = prefix | ((uint64_t)(uint32_t)(4 * t + 3) << shift); }
            if (cb2 < ku && ku <= cb2 + h2) { s_k = k - (int)cb2; s_prefix = prefix | ((uint64_t)(uint32_t)(4 * t + 2) << shift); }
            if (cb1 < ku && ku <= cb1 + h1) { s_k = k - (int)cb1; s_prefix = prefix | ((uint64_t)(uint32_t)(4 * t + 1) << shift); }
            if (cb0 < ku && ku <= cb0 + h0) { s_k = k - (int)cb0; s_prefix = prefix | ((uint64_t)(uint32_t)(4 * t + 0) << shift); }
        }
        __syncthreads();
    }

    // compact keys >= K* (exactly 1000 by key uniqueness)
    uint64_t kstar = s_prefix;
    for (int i = t; i < NA; i += 1024) {
        uint64_t key = ((uint64_t)ob[i] << 32) | (uint64_t)(0xFFFFFFFFu - (uint32_t)i);
        if (key >= kstar) {
            int p = atomicAdd(&s_cnt, 1);
            if (p < 1024) sbuf[p] = key;
        }
    }
    __syncthreads();

    // bitonic sort 1024 descending by (conf, -index)
    for (int k = 2; k <= 1024; k <<= 1) {
        for (int j = k >> 1; j > 0; j >>= 1) {
            int ixj = t ^ j;
            if (ixj > t) {
                uint64_t A = sbuf[t], Bv = sbuf[ixj];
                bool descBlock = ((t & k) == 0);
                bool sw = descBlock ? (A < Bv) : (A > Bv);
                if (sw) { sbuf[t] = Bv; sbuf[ixj] = A; }
            }
            __syncthreads();
        }
    }

    if (t < PRE_TOPK) {
        uint64_t key = sbuf[t];
        uint32_t u = (uint32_t)(key >> 32);
        uint32_t fb = (u & 0x80000000u) ? (u ^ 0x80000000u) : ~u;
        float val = __uint_as_float(fb);
        int idx = (int)(0xFFFFFFFFu - (uint32_t)(key & 0xFFFFFFFFull));
        size_t g = (size_t)b * NA + idx;
        float4 bx = *(const float4*)(box + g * 4);
        float cx = bx.x, cy = bx.y, w = bx.z, h = bx.w;
        size_t o = (size_t)b * PRE_TOPK + t;
        topv[o] = val;
        *(float4*)(bxyxy + o * 4) = make_float4(cx - w * 0.5f, cy - h * 0.5f,
                                                cx + w * 0.5f, cy + h * 0.5f);
        topcls[o] = clsid[g];
    }
}

// ---------------- Kernel 3: pairwise IoU bitmask (full GPU) ----------------
__device__ __forceinline__ int bslot(int j) { return j + (j >> 6); }

__global__ __launch_bounds__(256) void k_iou(
    const float* __restrict__ bxyxy, unsigned long long* __restrict__ mask)
{
    __shared__ float4 boxes[PRE_TOPK + 16];   // padded: lane stride 65 float4 -> 2-way (free)
    int b = blockIdx.y;
    int t = threadIdx.x;
    const float4* bp = (const float4*)(bxyxy + (size_t)b * PRE_TOPK * 4);
    for (int i = t; i < PRE_TOPK; i += 256) boxes[bslot(i)] = bp[i];
    __syncthreads();

    int r_local = t >> 4, w = t & 15;
    int row = blockIdx.x * 16 + r_local;
    if (row >= PRE_TOPK) return;

    float4 bi = boxes[bslot(row)];
    float area_i = (bi.z - bi.x) * (bi.w - bi.y);
    unsigned long long bits = 0;
    int j0 = w * 64;
    #pragma unroll 4
    for (int jj = 0; jj < 64; ++jj) {
        int j = j0 + jj;
        if (j >= PRE_TOPK) break;
        if (j <= row) continue;
        float4 bj = boxes[bslot(j)];
        float lx = fmaxf(bi.x, bj.x), ly = fmaxf(bi.y, bj.y);
        float rx = fminf(bi.z, bj.z), ry = fminf(bi.w, bj.w);
        float iw = fmaxf(rx - lx, 0.f), ih = fmaxf(ry - ly, 0.f);
        float inter = iw * ih;
        float area_j = (bj.z - bj.x) * (bj.w - bj.y);
        float iou = inter / (area_i + area_j - inter + 1e-7f);
        if (iou > 0.45f) bits |= (1ull << jj);
    }
    mask[((size_t)b * PRE_TOPK + row) * 16 + w] = bits;
}

// ---------------- Kernel 4: leader-jump NMS walk + emit ----------------
__global__ __launch_bounds__(1024) void k_nms(
    const unsigned long long* __restrict__ mask, const float* __restrict__ topv,
    const float* __restrict__ bxyxy, const int* __restrict__ topcls,
    float* __restrict__ out)
{
    int b = blockIdx.x;
    int t = threadIdx.x;

    __shared__ __align__(16) unsigned long long smask[PRE_TOPK * 16];  // 128 KB
    __shared__ float sv[PRE_TOPK];
    __shared__ unsigned long long s_valid[16];
    __shared__ int kept[MAX_DET];
    __shared__ int s_cnt;

    for (int i = t; i < PRE_TOPK; i += 1024) sv[i] = topv[(size_t)b * PRE_TOPK + i];
    {
        const ulonglong2* src = (const ulonglong2*)(mask + (size_t)b * PRE_TOPK * 16);
        ulonglong2* dst = (ulonglong2*)smask;
        for (int i = t; i < PRE_TOPK * 8; i += 1024) dst[i] = src[i];
    }
    __syncthreads();

    {
        bool pred = (t < PRE_TOPK) && (sv[t] > 0.0f);
        unsigned long long bal = __ballot(pred);
        if ((t & 63) == 0) s_valid[t >> 6] = bal;
    }
    __syncthreads();

    if (t < 64) {   // wave 0: leader-jump walk (one iteration per KEPT box)
        int w = t;
        unsigned long long supp = 0;
        unsigned long long valid = (w < 16) ? s_valid[w] : 0ull;
        int base = w * 64;
        int cur = -1;
        int cnt = 0;
        while (cnt < MAX_DET) {
            unsigned long long gt;
            if (cur < base)            gt = ~0ull;
            else if (cur - base >= 63) gt = 0ull;
            else                       gt = (~0ull) << (cur - base + 1);
            unsigned long long cand = valid & ~supp & gt;
            int idx = cand ? (base + __builtin_ctzll(cand)) : 0x7FFFFFFF;
            #pragma unroll
            for (int off = 8; off >= 1; off >>= 1) {
                int o = __shfl_xor(idx, off);
                idx = (o < idx) ? o : idx;
            }
            int nxt = __shfl(idx, 0);
            if (nxt == 0x7FFFFFFF) break;
            if (t == 0) kept[cnt] = nxt;
            ++cnt;
            if (w < 16) supp |= smask[nxt * 16 + w];
            cur = nxt;
        }
        if (t == 0) s_cnt = cnt;
    }
    __syncthreads();

    int cnt = s_cnt; if (cnt > MAX_DET) cnt = MAX_DET;
    if (t == 0) out[b] = (float)cnt;                       // num_dets (B,1)
    if (t < MAX_DET) {
        bool valid = t < cnt;
        float bx0 = 0.f, bx1 = 0.f, bx2 = 0.f, bx3 = 0.f, sc = 0.f, cl = 0.f;
        if (valid) {
            int p = kept[t];
            size_t o = (size_t)b * PRE_TOPK + p;
            float4 bb = *(const float4*)(bxyxy + o * 4);
            bx0 = bb.x; bx1 = bb.y; bx2 = bb.z; bx3 = bb.w;
            sc = sv[p];
            cl = (float)topcls[o];
        }
        size_t db = 32 + ((size_t)b * MAX_DET + t) * 4;
        out[db + 0] = bx0; out[db + 1] = bx1; out[db + 2] = bx2; out[db + 3] = bx3;
        out[32 + 12800 + (size_t)b * MAX_DET + t] = sc;    // det_scores
        out[32 + 16000 + (size_t)b * MAX_DET + t] = cl;    // det_classes
    }
}

// ---------------- launch ----------------
extern "C" void kernel_launch(void* const* d_in, const int* in_sizes, int n_in,
                              void* d_out, int out_size, void* d_ws, size_t ws_size,
                              hipStream_t stream)
{
    const float* p3 = (const float*)d_in[0];
    const float* p4 = (const float*)d_in[1];
    const float* p5 = (const float*)d_in[2];
    float* out = (float*)d_out;

    char* ws = (char*)d_ws;
    size_t off_mask = 0;                                       // 32*1000*16*8 = 4,096,000
    size_t off_conf = off_mask + (size_t)NB * PRE_TOPK * 16 * 8;
    size_t off_cls  = off_conf + (size_t)NB * NA * 4;
    size_t off_box  = off_cls  + (size_t)NB * NA * 4;
    size_t off_topv = off_box  + (size_t)NB * NA * 4 * 4;
    size_t off_topc = off_topv + (size_t)NB * PRE_TOPK * 4;
    size_t off_bx   = off_topc + (size_t)NB * PRE_TOPK * 4;

    unsigned long long* mask = (unsigned long long*)(ws + off_mask);
    float* conf   = (float*)(ws + off_conf);
    int*   clsid  = (int*)(ws + off_cls);
    float* box    = (float*)(ws + off_box);
    float* topv   = (float*)(ws + off_topv);
    int*   topcls = (int*)(ws + off_topc);
    float* bxyxy  = (float*)(ws + off_bx);

    k_decode<<<525, 128, 0, stream>>>(p3, p4, p5, conf, clsid, box);
    k_select<<<NB, 1024, 0, stream>>>(conf, box, clsid, topv, bxyxy, topcls);
    k_iou<<<dim3((PRE_TOPK + 15) / 16, NB), 256, 0, stream>>>(bxyxy, mask);
    k_nms<<<NB, 1024, 0, stream>>>(mask, topv, bxyxy, topcls, out);
}

// Round 8
// 151.033 us; speedup vs baseline: 1.0251x; 1.0251x over previous
//
#include <hip/hip_runtime.h>
#include <math.h>

#define NCLS 80
#define NA 8400
#define NB 32
#define NO 144
#define PRE_TOPK 1000
#define MAX_DET 100

// ---------------- Kernel 1: decode, scalar + 2-deep load-group pipeline ----
__device__ __forceinline__ float dfl16(const float* v) {
    float mm = v[0];
    #pragma unroll
    for (int r = 1; r < 16; ++r) mm = fmaxf(mm, v[r]);
    float sum = 0.f, d = 0.f;
    #pragma unroll
    for (int r = 0; r < 16; ++r) {
        float e = __expf(v[r] - mm);
        sum += e;
        d += e * (float)r;
    }
    return d * (1.0f / sum);
}

__device__ __forceinline__ void cls20(const float* v, int chbase, float& best, int& bid) {
    float m = v[0]; int ii = 0;
    #pragma unroll
    for (int c = 1; c < 20; ++c) if (v[c] > m) { m = v[c]; ii = c; }
    if (m > best) { best = m; bid = chbase + ii; }
}

template<int HW, int WDIM, int S>
__device__ __forceinline__ void decode_store(
    const float* __restrict__ src, int g, int aoff,
    float* __restrict__ conf, int* __restrict__ clsid, float* __restrict__ box)
{
    int b = g / HW;
    int pos = g - b * HW;
    float ax = (float)(pos % WDIM) + 0.5f;
    float ay = (float)(pos / WDIM) + 0.5f;
    const float* base = src + (size_t)b * (NO * HW) + pos;

    // Pipeline: keep two group-pairs of loads in flight (~32-40 loads
    // outstanding) while processing the trailing pair. All arrays statically
    // indexed (full unroll) -> registers, no scratch.
    float g0[16], g1[16], g2[16], g3[16];
    float c0[20], c1[20], c2[20], c3[20];

    // P0: issue DFL groups 0,1
    #pragma unroll
    for (int r = 0; r < 16; ++r) g0[r] = base[(size_t)r * HW];
    #pragma unroll
    for (int r = 0; r < 16; ++r) g1[r] = base[(size_t)(16 + r) * HW];
    // P1: issue DFL groups 2,3
    #pragma unroll
    for (int r = 0; r < 16; ++r) g2[r] = base[(size_t)(32 + r) * HW];
    #pragma unroll
    for (int r = 0; r < 16; ++r) g3[r] = base[(size_t)(48 + r) * HW];
    // process groups 0,1 (waits only on their loads; g2/g3 stay in flight)
    float d0 = dfl16(g0);
    float d1 = dfl16(g1);
    // P2: issue class chunks 0,1
    #pragma unroll
    for (int c = 0; c < 20; ++c) c0[c] = base[(size_t)(64 + c) * HW];
    #pragma unroll
    for (int c = 0; c < 20; ++c) c1[c] = base[(size_t)(84 + c) * HW];
    // process groups 2,3
    float d2 = dfl16(g2);
    float d3 = dfl16(g3);
    // P3: issue class chunks 2,3
    #pragma unroll
    for (int c = 0; c < 20; ++c) c2[c] = base[(size_t)(104 + c) * HW];
    #pragma unroll
    for (int c = 0; c < 20; ++c) c3[c] = base[(size_t)(124 + c) * HW];
    // process class chunks 0,1
    float best = -INFINITY; int bid = 0;
    cls20(c0, 0, best, bid);
    cls20(c1, 20, best, bid);
    // process class chunks 2,3
    cls20(c2, 40, best, bid);
    cls20(c3, 60, best, bid);

    float conf_v = 1.0f / (1.0f + __expf(-best));   // sigmoid(max)==max(sigmoid)

    float x1 = ax - d0, y1 = ay - d1;
    float x2 = ax + d2, y2 = ay + d3;
    float cx = ((x1 + x2) * 0.5f) * (float)S;
    float cy = ((y1 + y2) * 0.5f) * (float)S;
    float w  = (x2 - x1) * (float)S;
    float h  = (y2 - y1) * (float)S;

    size_t gid = (size_t)b * NA + aoff + pos;
    conf[gid]  = conf_v;
    clsid[gid] = bid;
    *(float4*)(box + gid * 4) = make_float4(cx, cy, w, h);
}

__global__ __launch_bounds__(256, 4) void k_decode(
    const float* __restrict__ p3, const float* __restrict__ p4, const float* __restrict__ p5,
    float* __restrict__ conf, int* __restrict__ clsid, float* __restrict__ box)
{
    int blk = blockIdx.x;
    int t = threadIdx.x;
    if (blk < 800) {            // p3: 32 * 6400 threads
        int g = blk * 256 + t;
        decode_store<6400, 80, 8>(p3, g, 0, conf, clsid, box);
    } else if (blk < 1000) {    // p4
        int g = (blk - 800) * 256 + t;
        decode_store<1600, 40, 16>(p4, g, 6400, conf, clsid, box);
    } else {                    // p5
        int g = (blk - 1000) * 256 + t;
        decode_store<400, 20, 32>(p5, g, 8000, conf, clsid, box);
    }
}

// ------- Kernel 2: fused top-1000 + on-demand-IoU NMS walk + emit ----------
// Phase A (select+sort): ob[8400] @0, hist @36656, sbuf @37680 (persists)
// Phase B/C (walk):      boxes @0 (16000B), sv @16000, kept @20000
#define SM_SV    16000
#define SM_KEPT  20000
#define SM_HIST  36656
#define SM_SBUF  37680
#define SM_SIZE  45872

__device__ __forceinline__ uint32_t ord_bits(float f) {
    uint32_t u = __float_as_uint(f);
    return (u & 0x80000000u) ? ~u : (u | 0x80000000u);
}

__global__ __launch_bounds__(1024) void k_post(
    const float* __restrict__ conf, const float* __restrict__ box, const int* __restrict__ clsid,
    float* __restrict__ out)
{
    int b = blockIdx.x;
    int t = threadIdx.x;
    int lane = t & 63;

    __shared__ __align__(16) char smem[SM_SIZE];
    __shared__ uint64_t s_prefix;
    __shared__ int s_k;
    __shared__ int s_cnt;     // compaction cursor (phase A only)
    __shared__ int s_nkept;   // NMS keep count (phase C only — NOT reused)
    __shared__ int s_cur;     // current leader index
    __shared__ unsigned long long s_supp[16];
    __shared__ unsigned long long s_valid[16];

    uint32_t* ob   = (uint32_t*)smem;
    uint32_t* hist = (uint32_t*)(smem + SM_HIST);
    uint64_t* sbuf = (uint64_t*)(smem + SM_SBUF);

    // ---- phase A: thresholded ordered keys ----
    const float* cf = conf + (size_t)b * NA;
    for (int i = t; i < NA; i += 1024) {
        float c = cf[i];
        float cm = (c > 0.25f) ? c : -1.0f;
        ob[i] = ord_bits(cm);
    }
    if (t == 0) { s_prefix = 0; s_k = PRE_TOPK; s_cnt = 0; s_nkept = 0; s_cur = -1; }
    sbuf[t] = 0;
    __syncthreads();

    // radix-select exact rank-1000 key; wave-aggregated histogram atomics
    for (int pass = 0; pass < 8; ++pass) {
        int shift = 56 - 8 * pass;
        if (t < 256) hist[t] = 0;
        __syncthreads();
        uint64_t prefix = s_prefix;
        int k = s_k;
        for (int i = t; i < NA; i += 1024) {
            uint64_t key = ((uint64_t)ob[i] << 32) | (uint64_t)(0xFFFFFFFFu - (uint32_t)i);
            bool match = (pass == 0) || (((key ^ prefix) >> (64 - 8 * pass)) == 0);
            uint32_t d = (uint32_t)(key >> shift) & 255u;
            if (match) {
                uint64_t m = __ballot(1);
                #pragma unroll
                for (int bb = 0; bb < 8; ++bb) {
                    uint64_t bal = __ballot((d >> bb) & 1u);
                    m &= ((d >> bb) & 1u) ? bal : ~bal;
                }
                if ((m & ((1ull << lane) - 1ull)) == 0ull)
                    atomicAdd(&hist[d], (uint32_t)__popcll(m));
            }
        }
        __syncthreads();
        if (t < 64) {   // wave-0 suffix-scan digit selection
            uint32_t h0 = hist[4 * t + 0], h1 = hist[4 * t + 1];
            uint32_t h2 = hist[4 * t + 2], h3 = hist[4 * t + 3];
            uint32_t part = h0 + h1 + h2 + h3;
            uint32_t s = part;
            #pragma unroll
            for (int off = 1; off < 64; off <<= 1) {
                uint32_t v = __shfl_down(s, off);
                if (t + off < 64) s += v;
            }
            uint32_t cb3 = s - part;
            uint32_t cb2 = cb3 + h3;
            uint32_t cb1 = cb2 + h2;
            uint32_t cb0 = cb1 + h1;
            uint32_t ku = (uint32_t)k;
            if (cb3 < ku && ku <= cb3 + h3) { s_k = k - (int)cb3; s_prefix = prefix | ((uint64_t)(uint32_t)(4 * t + 3) << shift); }
            if (cb2 < ku && ku <= cb2 + h2) { s_k = k - (int)cb2; s_prefix = prefix | ((uint64_t)(uint32_t)(4 * t + 2) << shift); }
            if (cb1 < ku && ku <= cb1 + h1) { s_k = k - (int)cb1; s_prefix = prefix | ((uint64_t)(uint32_t)(4 * t + 1) << shift); }
            if (cb0 < ku && ku <= cb0 + h0) { s_k = k - (int)cb0; s_prefix = prefix | ((uint64_t)(uint32_t)(4 * t + 0) << shift); }
        }
        __syncthreads();
    }

    // compact keys >= K* (exactly 1000 by key uniqueness)
    uint64_t kstar = s_prefix;
    for (int i = t; i < NA; i += 1024) {
        uint64_t key = ((uint64_t)ob[i] << 32) | (uint64_t)(0xFFFFFFFFu - (uint32_t)i);
        if (key >= kstar) {
            int p = atomicAdd(&s_cnt, 1);
            if (p < 1024) sbuf[p] = key;
        }
    }
    __syncthreads();

    // bitonic sort 1024 descending by (conf, -index)
    for (int k = 2; k <= 1024; k <<= 1) {
        for (int j = k >> 1; j > 0; j >>= 1) {
            int ixj = t ^ j;
            if (ixj > t) {
                uint64_t A = sbuf[t], Bv = sbuf[ixj];
                bool descBlock = ((t & k) == 0);
                bool sw = descBlock ? (A < Bv) : (A > Bv);
                if (sw) { sbuf[t] = Bv; sbuf[ixj] = A; }
            }
            __syncthreads();
        }
    }
    // ob/hist dead from here; smem front reused for boxes/sv/kept

    // ---- phase B: boxes/scores to LDS ----
    float4* boxes = (float4*)smem;
    float*  sv    = (float*)(smem + SM_SV);
    int*    kept  = (int*)(smem + SM_KEPT);

    if (t < PRE_TOPK) {
        uint64_t key = sbuf[t];
        uint32_t u = (uint32_t)(key >> 32);
        uint32_t fb = (u & 0x80000000u) ? (u ^ 0x80000000u) : ~u;
        sv[t] = __uint_as_float(fb);
        int idx = (int)(0xFFFFFFFFu - (uint32_t)(key & 0xFFFFFFFFull));
        size_t g = (size_t)b * NA + idx;
        float4 bx = *(const float4*)(box + g * 4);
        float cx = bx.x, cy = bx.y, w = bx.z, h = bx.w;
        boxes[t] = make_float4(cx - w * 0.5f, cy - h * 0.5f, cx + w * 0.5f, cy + h * 0.5f);
    }
    if (t < 16) s_supp[t] = 0;
    __syncthreads();

    {   // validity bitmap (scores sorted desc; wave w's ballot = word w)
        bool pred = (t < PRE_TOPK) && (sv[t] > 0.0f);
        unsigned long long bal = __ballot(pred);
        if ((t & 63) == 0) s_valid[t >> 6] = bal;
    }
    __syncthreads();

    // ---- phase C: leader-jump walk with ON-DEMAND suppression rows ----
    for (int iter = 0; iter < MAX_DET; ++iter) {
        if (t < 64) {   // wave 0: next leader = min{ idx > cur, valid, !supp }
            int cur = s_cur;
            unsigned long long cand = (t < 16) ? (s_valid[t] & ~s_supp[t]) : 0ull;
            int base = t * 64;
            unsigned long long gt;
            if (cur < base)            gt = ~0ull;
            else if (cur - base >= 63) gt = 0ull;
            else                       gt = (~0ull) << (cur - base + 1);
            cand &= gt;
            int idx = cand ? (base + __builtin_ctzll(cand)) : 0x7FFFFFFF;
            #pragma unroll
            for (int off = 8; off >= 1; off >>= 1) {
                int o = __shfl_xor(idx, off);
                idx = (o < idx) ? o : idx;
            }
            if (t == 0) s_cur = (idx == 0x7FFFFFFF) ? -2 : idx;
        }
        __syncthreads();
        int L = s_cur;
        if (L < 0) break;                        // uniform: read after barrier
        if (t == 0) { kept[iter] = L; s_nkept = iter + 1; }

        // all threads: leader L's suppression row (1 IoU per thread)
        bool sup = false;
        if (t < PRE_TOPK && t > L) {
            float4 bi = boxes[L];                // same-address broadcast
            float4 bj = boxes[t];
            float area_i = (bi.z - bi.x) * (bi.w - bi.y);
            float area_j = (bj.z - bj.x) * (bj.w - bj.y);
            float lx = fmaxf(bi.x, bj.x), ly = fmaxf(bi.y, bj.y);
            float rx = fminf(bi.z, bj.z), ry = fminf(bi.w, bj.w);
            float iw = fmaxf(rx - lx, 0.f), ih = fmaxf(ry - ly, 0.f);
            float inter = iw * ih;
            float iou = inter / (area_i + area_j - inter + 1e-7f);
            sup = iou > 0.45f;
        }
        unsigned long long bal = __ballot(sup);
        if ((t & 63) == 0) s_supp[t >> 6] |= bal;   // wave w owns word w
        __syncthreads();
    }

    // ---- emit ----
    int cnt = s_nkept; if (cnt > MAX_DET) cnt = MAX_DET;
    if (t == 0) out[b] = (float)cnt;                       // num_dets (B,1)
    if (t < MAX_DET) {
        bool valid = t < cnt;
        float bx0 = 0.f, bx1 = 0.f, bx2 = 0.f, bx3 = 0.f, sc = 0.f, cl = 0.f;
        if (valid) {
            int p = kept[t];
            float4 bb = boxes[p];
            bx0 = bb.x; bx1 = bb.y; bx2 = bb.z; bx3 = bb.w;
            sc = sv[p];
            uint64_t key = sbuf[p];
            int idx = (int)(0xFFFFFFFFu - (uint32_t)(key & 0xFFFFFFFFull));
            cl = (float)clsid[(size_t)b * NA + idx];
        }
        size_t db = 32 + ((size_t)b * MAX_DET + t) * 4;
        out[db + 0] = bx0; out[db + 1] = bx1; out[db + 2] = bx2; out[db + 3] = bx3;
        out[32 + 12800 + (size_t)b * MAX_DET + t] = sc;    // det_scores
        out[32 + 16000 + (size_t)b * MAX_DET + t] = cl;    // det_classes
    }
}

// ---------------- launch ----------------
extern "C" void kernel_launch(void* const* d_in, const int* in_sizes, int n_in,
                              void* d_out, int out_size, void* d_ws, size_t ws_size,
                              hipStream_t stream)
{
    const float* p3 = (const float*)d_in[0];
    const float* p4 = (const float*)d_in[1];
    const float* p5 = (const float*)d_in[2];
    float* out = (float*)d_out;

    char* ws = (char*)d_ws;
    size_t off_conf = 0;
    size_t off_cls  = off_conf + (size_t)NB * NA * 4;
    size_t off_box  = off_cls  + (size_t)NB * NA * 4;        // 16B-aligned

    float* conf  = (float*)(ws + off_conf);
    int*   clsid = (int*)(ws + off_cls);
    float* box   = (float*)(ws + off_box);

    k_decode<<<1050, 256, 0, stream>>>(p3, p4, p5, conf, clsid, box);
    k_post<<<NB, 1024, 0, stream>>>(conf, box, clsid, out);
}